// Round 1
// baseline (527.590 us; speedup 1.0000x reference)
//
#include <hip/hip_runtime.h>

// Problem: out = dequant( int8_gemm( quant(x, in_scale), quant(w, absmax/127) ) + b_q )
// M = 4*2048 = 8192, K = 1600, N = 6400.

#define M_DIM 8192
#define K_DIM 1600
#define N_DIM 6400
#define QMAXF 127.0f

typedef __attribute__((ext_vector_type(4))) int int4v;

// ---------------- ws layout ----------------
// [0, 4)            : uint bits of max|w|  (atomicMax target; memset to 0 each call)
// [256, 256+M*K)    : x_q  int8, row-major [M][K]
// [.. , ..  +N*K)   : wT_q int8, row-major [N][K]  (transposed weight)

__device__ __forceinline__ void load_lds16(const void* gptr, void* lptr) {
    // global -> LDS direct, 16B per lane; LDS dest = wave-uniform base + lane*16
    __builtin_amdgcn_global_load_lds((__attribute__((address_space(1))) void*)gptr,
                                     (__attribute__((address_space(3))) void*)lptr,
                                     16, 0, 0);
}

// ---------------- absmax(weight) reduction ----------------
__global__ void wmax_kernel(const float* __restrict__ w,
                            unsigned int* __restrict__ wmax_bits, int n4) {
    const float4* w4 = (const float4*)w;
    int i = blockIdx.x * blockDim.x + threadIdx.x;
    int stride = gridDim.x * blockDim.x;
    float m = 0.0f;
    for (; i < n4; i += stride) {
        float4 v = w4[i];
        m = fmaxf(m, fmaxf(fmaxf(fabsf(v.x), fabsf(v.y)),
                           fmaxf(fabsf(v.z), fabsf(v.w))));
    }
#pragma unroll
    for (int off = 32; off > 0; off >>= 1)
        m = fmaxf(m, __shfl_down(m, off, 64));
    if ((threadIdx.x & 63) == 0)
        atomicMax(wmax_bits, __float_as_uint(m));  // m >= 0 -> uint order == float order
}

// ---------------- quantize x -> int8 [M][K] ----------------
__global__ void quantx_kernel(const float* __restrict__ x, signed char* __restrict__ xq,
                              const float* __restrict__ in_scale_p, int n4) {
    int i = blockIdx.x * blockDim.x + threadIdx.x;
    if (i >= n4) return;
    float s = *in_scale_p;
    float4 v = ((const float4*)x)[i];
    // IEEE division + rintf (round-half-even) to match numpy bit-exactly
    float a = fminf(fmaxf(rintf(v.x / s), -128.0f), 127.0f);
    float b = fminf(fmaxf(rintf(v.y / s), -128.0f), 127.0f);
    float c = fminf(fmaxf(rintf(v.z / s), -128.0f), 127.0f);
    float d = fminf(fmaxf(rintf(v.w / s), -128.0f), 127.0f);
    char4 packed = make_char4((signed char)a, (signed char)b,
                              (signed char)c, (signed char)d);
    ((char4*)xq)[i] = packed;
}

// ---------------- quantize + transpose w -> int8 [N][K] ----------------
__global__ void quantw_kernel(const float* __restrict__ w, signed char* __restrict__ wT,
                              const unsigned int* __restrict__ wmax_bits) {
    __shared__ signed char tile[32][33];  // +1 pad breaks bank collisions
    float wscale = __uint_as_float(*wmax_bits) / QMAXF;
    int n0 = blockIdx.x * 32;
    int k0 = blockIdx.y * 32;
    int tx = threadIdx.x;  // 0..31
    int ty = threadIdx.y;  // 0..7
#pragma unroll
    for (int p = 0; p < 4; ++p) {
        int kk = ty + p * 8;
        float v = w[(size_t)(k0 + kk) * N_DIM + n0 + tx];  // coalesced along n
        float q = fminf(fmaxf(rintf(v / wscale), -128.0f), 127.0f);
        tile[kk][tx] = (signed char)q;
    }
    __syncthreads();
#pragma unroll
    for (int p = 0; p < 4; ++p) {
        int nn = ty + p * 8;
        wT[(size_t)(n0 + nn) * K_DIM + k0 + tx] = tile[tx][nn];  // coalesced along k
    }
}

// ---------------- int8 GEMM, 128x128 tile, BK=64, fused epilogue ----------------
// 4 waves in 2x2; each wave owns 64x64 = 4x4 tiles of mfma_i32_16x16x64_i8.
__global__ __launch_bounds__(256, 2) void gemm_i8_kernel(
        const signed char* __restrict__ xq, const signed char* __restrict__ wTq,
        const float* __restrict__ bias, const unsigned int* __restrict__ wmax_bits,
        const float* __restrict__ in_scale_p, const float* __restrict__ out_scale_p,
        float* __restrict__ out) {
    __shared__ signed char A_lds[128 * 64];  // 8 KB  [m][k]
    __shared__ signed char B_lds[128 * 64];  // 8 KB  [n][k]

    const int tid   = threadIdx.x;
    const int wave  = tid >> 6;
    const int lane  = tid & 63;
    const int quad  = lane >> 4;
    const int l15   = lane & 15;
    const int waveM = wave >> 1;  // 0..1
    const int waveN = wave & 1;   // 0..1

    const int blockN0 = blockIdx.x * 128;
    const int blockM0 = blockIdx.y * 128;

    const signed char* Ag = xq  + (size_t)blockM0 * K_DIM;
    const signed char* Bg = wTq + (size_t)blockN0 * K_DIM;

    // staging: per issue, 256 threads x 16B = 64 rows of 64B
    const int srow = wave * 16 + (lane >> 2);   // row within 64-row chunk
    const int scol = (lane & 3) * 16;           // byte offset within 64B row

    int4v acc[4][4];
    const int4v zero4 = {0, 0, 0, 0};
#pragma unroll
    for (int i = 0; i < 4; ++i)
#pragma unroll
        for (int j = 0; j < 4; ++j) acc[i][j] = zero4;

    for (int k0 = 0; k0 < K_DIM; k0 += 64) {
#pragma unroll
        for (int t = 0; t < 2; ++t) {
            const int r = t * 64 + srow;
            // LDS base must be wave-uniform; HW adds lane*16
            load_lds16(Ag + (size_t)r * K_DIM + k0 + scol,
                       &A_lds[(t * 64 + wave * 16) * 64]);
            load_lds16(Bg + (size_t)r * K_DIM + k0 + scol,
                       &B_lds[(t * 64 + wave * 16) * 64]);
        }
        __syncthreads();

        int4v a[4], b[4];
#pragma unroll
        for (int mt = 0; mt < 4; ++mt)
            a[mt] = *(const int4v*)&A_lds[(waveM * 64 + mt * 16 + l15) * 64 + quad * 16];
#pragma unroll
        for (int nt = 0; nt < 4; ++nt)
            b[nt] = *(const int4v*)&B_lds[(waveN * 64 + nt * 16 + l15) * 64 + quad * 16];

#pragma unroll
        for (int mt = 0; mt < 4; ++mt)
#pragma unroll
            for (int nt = 0; nt < 4; ++nt)
                acc[mt][nt] = __builtin_amdgcn_mfma_i32_16x16x64_i8(a[mt], b[nt],
                                                                    acc[mt][nt], 0, 0, 0);
        __syncthreads();
    }

    // epilogue: + b_q, rescale, rint, clip, dequant
    const float s_in  = *in_scale_p;
    const float s_out = *out_scale_p;
    const float wscale = __uint_as_float(*wmax_bits) / QMAXF;
    const float bias_scale = s_in * wscale;         // fp32, same order as reference
    const float ratio = bias_scale / s_out;         // fp32 division

#pragma unroll
    for (int nt = 0; nt < 4; ++nt) {
        const int col = blockN0 + waveN * 64 + nt * 16 + l15;
        const int bq = (int)rintf(bias[col] / bias_scale);
#pragma unroll
        for (int mt = 0; mt < 4; ++mt) {
#pragma unroll
            for (int r = 0; r < 4; ++r) {
                const int row = blockM0 + waveM * 64 + mt * 16 + quad * 4 + r;
                const int av = acc[mt][nt][r] + bq;
                float f = rintf((float)av * ratio);
                f = fminf(fmaxf(f, -128.0f), 127.0f);
                out[(size_t)row * N_DIM + col] = f * s_out;
            }
        }
    }
}

extern "C" void kernel_launch(void* const* d_in, const int* in_sizes, int n_in,
                              void* d_out, int out_size, void* d_ws, size_t ws_size,
                              hipStream_t stream) {
    const float* x         = (const float*)d_in[0];
    const float* w         = (const float*)d_in[1];
    const float* bias      = (const float*)d_in[2];
    const float* in_scale  = (const float*)d_in[3];
    const float* out_scale = (const float*)d_in[4];
    float* out = (float*)d_out;

    unsigned char* ws = (unsigned char*)d_ws;
    unsigned int* wmax_bits = (unsigned int*)ws;
    signed char* xq  = (signed char*)(ws + 256);
    signed char* wTq = (signed char*)(ws + 256 + (size_t)M_DIM * K_DIM);

    // ws is poisoned 0xAA before every timed call -> re-init the reduction slot
    hipMemsetAsync(d_ws, 0, 256, stream);

    wmax_kernel<<<2560, 256, 0, stream>>>(w, wmax_bits, (K_DIM * N_DIM) / 4);

    quantx_kernel<<<(M_DIM * K_DIM / 4 + 255) / 256, 256, 0, stream>>>(
        x, xq, in_scale, M_DIM * K_DIM / 4);

    dim3 wgrid(N_DIM / 32, K_DIM / 32);
    quantw_kernel<<<wgrid, dim3(32, 8), 0, stream>>>(w, wTq, wmax_bits);

    dim3 ggrid(N_DIM / 128, M_DIM / 128);  // (50, 64)
    gemm_i8_kernel<<<ggrid, 256, 0, stream>>>(xq, wTq, bias, wmax_bits,
                                              in_scale, out_scale, out);
}